// Round 1
// baseline (364.711 us; speedup 1.0000x reference)
//
#include <hip/hip_runtime.h>
#include <hip/hip_bf16.h>

typedef __bf16 bf16_t;
typedef __bf16 bf16x8 __attribute__((ext_vector_type(8)));
typedef float f32x4 __attribute__((ext_vector_type(4)));

struct alignas(16) V16 { unsigned long long x, y; };

#define SCALE_ 0.14433756729740643f  // 1/sqrt(48)

static __device__ __forceinline__ bf16_t f2b(float f) {
  union { float f; unsigned u; } v; v.f = f;
  unsigned r = v.u + 0x7fffu + ((v.u >> 16) & 1u);
  unsigned short h = (unsigned short)(r >> 16);
  return __builtin_bit_cast(bf16_t, h);
}

static __device__ __forceinline__ f32x4 mfma16(bf16x8 a, bf16x8 b, f32x4 c) {
  return __builtin_amdgcn_mfma_f32_16x16x32_bf16(a, b, c, 0, 0, 0);
}

// ---- prep: W[k][n] (f32) -> Wt[n][k] (bf16) ----
template<int K, int N>
__global__ void k_convT(const float* __restrict__ W, bf16_t* __restrict__ Wt) {
  int idx = blockIdx.x * 256 + threadIdx.x;
  if (idx >= K * N) return;
  int n = idx / K, k = idx - n * K;
  Wt[idx] = f2b(W[k * N + n]);
}

// ---- prep: mem [512][384] f32 -> memh [8][512][64] bf16 (pad zero) ----
__global__ void k_memh(const float* __restrict__ mem, bf16_t* __restrict__ memh) {
  int idx = blockIdx.x * 256 + threadIdx.x;   // 8*512*64 = 262144
  int h = idx >> 15;
  int m = (idx >> 6) & 511;
  int d = idx & 63;
  float v = (d < 48) ? mem[m * 384 + h * 48 + d] : 0.f;
  memh[idx] = f2b(v);
}

// ---- prep: zero pad region d in [48,64) of kh [B*H*256][64] ----
__global__ void k_zpad(bf16_t* __restrict__ kh) {
  int i = blockIdx.x * 256 + threadIdx.x;     // 2 * 262144
  if (i >= 524288) return;
  int row = i >> 1, half = i & 1;
  V16 z; z.x = 0; z.y = 0;
  *(V16*)((char*)kh + row * 128 + 96 + half * 16) = z;
}

// ---- qkv GEMM: C[32768][1152] = X[32768][384] @ Wt^T + bias, scatter to padded per-head q/k/v ----
__global__ __launch_bounds__(256) void k_gemm_qkv(
    const float* __restrict__ X, const bf16_t* __restrict__ Wt,
    const float* __restrict__ bias,
    bf16_t* __restrict__ qh, bf16_t* __restrict__ kh, bf16_t* __restrict__ vh)
{
  __shared__ __align__(16) bf16_t As[128][32];
  __shared__ __align__(16) bf16_t Bs[128][32];
  const int tid = threadIdx.x;
  const int lane = tid & 63;
  const int wid = tid >> 6;
  const int wr = wid >> 1, wc = wid & 1;
  const int rowBase = blockIdx.x * 128;
  const int colBase = blockIdx.y * 128;
  f32x4 acc[4][4] = {};
  for (int k0 = 0; k0 < 384; k0 += 32) {
    __syncthreads();
#pragma unroll
    for (int i = 0; i < 2; ++i) {
      int c = i * 256 + tid;
      int r = c >> 2, kc = c & 3;
      const float* ap = X + (size_t)(rowBase + r) * 384 + k0 + kc * 8;
      float4 a0 = *(const float4*)ap;
      float4 a1 = *(const float4*)(ap + 4);
      bf16x8 t;
      t[0] = f2b(a0.x); t[1] = f2b(a0.y); t[2] = f2b(a0.z); t[3] = f2b(a0.w);
      t[4] = f2b(a1.x); t[5] = f2b(a1.y); t[6] = f2b(a1.z); t[7] = f2b(a1.w);
      *(bf16x8*)&As[r][kc * 8] = t;
      *(V16*)&Bs[r][kc * 8] = *(const V16*)&Wt[(size_t)(colBase + r) * 384 + k0 + kc * 8];
    }
    __syncthreads();
    bf16x8 af[4], bfr[4];
#pragma unroll
    for (int mb = 0; mb < 4; ++mb)
      af[mb] = *(const bf16x8*)&As[wr * 64 + mb * 16 + (lane & 15)][(lane >> 4) * 8];
#pragma unroll
    for (int nb = 0; nb < 4; ++nb)
      bfr[nb] = *(const bf16x8*)&Bs[wc * 64 + nb * 16 + (lane & 15)][(lane >> 4) * 8];
#pragma unroll
    for (int mb = 0; mb < 4; ++mb)
#pragma unroll
      for (int nb = 0; nb < 4; ++nb)
        acc[mb][nb] = mfma16(af[mb], bfr[nb], acc[mb][nb]);
  }
#pragma unroll
  for (int nb = 0; nb < 4; ++nb) {
    int col = colBase + wc * 64 + nb * 16 + (lane & 15);
    float bv = bias[col];
    int which = col / 384;
    int cc = col - which * 384;
    int h = cc / 48;
    int d = cc - h * 48;
    bf16_t* dst = (which == 0) ? qh : ((which == 1) ? kh : vh);
#pragma unroll
    for (int mb = 0; mb < 4; ++mb) {
#pragma unroll
      for (int r = 0; r < 4; ++r) {
        int row = rowBase + wr * 64 + mb * 16 + (lane >> 4) * 4 + r;
        int b = row >> 8, t = row & 255;
        dst[((size_t)(b * 8 + h) * 256 + t) * 64 + d] = f2b(acc[mb][nb][r] + bv);
      }
    }
  }
}

// ---- attention: flash-style, per (qchunk, h, b), 4 waves x 16 queries ----
__global__ __launch_bounds__(256) void k_attn(
    const bf16_t* __restrict__ qh, const bf16_t* __restrict__ kh,
    const bf16_t* __restrict__ vh, const bf16_t* __restrict__ memh,
    const float* __restrict__ gate, bf16_t* __restrict__ yw)
{
  __shared__ __align__(16) char Ks[8192];     // K tile [key 64][d 64] bf16, xor-swizzled
  __shared__ __align__(16) char Vt[8192];     // V^T tile [d 64][key 64] bf16, xor-swizzled
  __shared__ __align__(16) char Ps[4][2048];  // per-wave P [q 16][key 64] bf16, xor-swizzled
  const int tid = threadIdx.x;
  const int lane = tid & 63;
  const int w = tid >> 6;
  const int qc = blockIdx.x, h = blockIdx.y, b = blockIdx.z;
  const int bh = b * 8 + h;
  const int qw = qc * 64 + w * 16;

  bf16x8 qf0, qf1;
  {
    const bf16_t* qp = qh + ((size_t)(bh << 8) + qw + (lane & 15)) * 64 + (lane >> 4) * 8;
    qf0 = *(const bf16x8*)qp;
    qf1 = *(const bf16x8*)(qp + 32);
  }
  float m_r[4] = {-1e30f, -1e30f, -1e30f, -1e30f};
  float l_r[4] = {0.f, 0.f, 0.f, 0.f};
  f32x4 o0 = {}, o1 = {}, o2 = {};
  const int nself = (qc == 0) ? 1 : 2;
  const int nt = 8 + nself;

  for (int it = 0; it < nt; ++it) {
    const bf16_t *ksrc, *vsrc;
    int kb0;
    if (it < 8) {
      ksrc = vsrc = memh + (size_t)(h * 512 + it * 64) * 64;
      kb0 = -1;
    } else {
      int st = qc - (nself - 1) + (it - 8);
      ksrc = kh + ((size_t)(bh << 8) + st * 64) * 64;
      vsrc = vh + ((size_t)(bh << 8) + st * 64) * 64;
      kb0 = st * 64;
    }
    __syncthreads();
    {
      int key = tid & 63;
      int dg0 = tid >> 6;
#pragma unroll
      for (int half = 0; half < 2; ++half) {
        int dg = dg0 + half * 4;
        V16 kvv = *(const V16*)(ksrc + key * 64 + dg * 8);
        *(V16*)(Ks + ((key * 128 + dg * 16) ^ ((key & 7) << 4))) = kvv;
        bf16x8 vv = *(const bf16x8*)(vsrc + key * 64 + dg * 8);
#pragma unroll
        for (int j = 0; j < 8; ++j) {
          int d = dg * 8 + j;
          *(bf16_t*)(Vt + ((d * 128 + key * 2) ^ ((d & 7) << 4))) = vv[j];
        }
      }
    }
    __syncthreads();

    // S = Q K^T  (d padded to 64; K pads are zero)
    f32x4 s[4];
#pragma unroll
    for (int kb = 0; kb < 4; ++kb) {
      int key = kb * 16 + (lane & 15);
      int dp = (lane >> 4) * 8;
      bf16x8 k0v = *(const bf16x8*)(Ks + ((key * 128 + dp * 2) ^ ((key & 7) << 4)));
      bf16x8 k1v = *(const bf16x8*)(Ks + ((key * 128 + (dp + 32) * 2) ^ ((key & 7) << 4)));
      f32x4 t = {};
      t = mfma16(qf0, k0v, t);
      t = mfma16(qf1, k1v, t);
      s[kb] = t;
    }
    // mask + scale
    float mt[4] = {-1e30f, -1e30f, -1e30f, -1e30f};
#pragma unroll
    for (int kb = 0; kb < 4; ++kb) {
#pragma unroll
      for (int r = 0; r < 4; ++r) {
        float sv = s[kb][r] * SCALE_;
        if (kb0 >= 0) {
          int j = kb0 + kb * 16 + (lane & 15);
          int q = qw + (lane >> 4) * 4 + r;
          if (!(j <= q && q - j <= 64)) sv = -1e30f;
        }
        s[kb][r] = sv;
        mt[r] = fmaxf(mt[r], sv);
      }
    }
#pragma unroll
    for (int r = 0; r < 4; ++r) {
#pragma unroll
      for (int off = 1; off < 16; off <<= 1)
        mt[r] = fmaxf(mt[r], __shfl_xor(mt[r], off));
    }
    float alpha[4], lsum[4];
#pragma unroll
    for (int r = 0; r < 4; ++r) {
      float mn = fmaxf(m_r[r], mt[r]);
      alpha[r] = __expf(m_r[r] - mn);
      m_r[r] = mn;
      lsum[r] = 0.f;
    }
#pragma unroll
    for (int kb = 0; kb < 4; ++kb)
#pragma unroll
      for (int r = 0; r < 4; ++r) {
        float p = __expf(s[kb][r] - m_r[r]);
        s[kb][r] = p;
        lsum[r] += p;
      }
#pragma unroll
    for (int r = 0; r < 4; ++r) {
#pragma unroll
      for (int off = 1; off < 16; off <<= 1)
        lsum[r] += __shfl_xor(lsum[r], off);
      l_r[r] = l_r[r] * alpha[r] + lsum[r];
      o0[r] *= alpha[r]; o1[r] *= alpha[r]; o2[r] *= alpha[r];
    }
    // P -> LDS (per-wave buffer)
    char* myP = Ps[w];
#pragma unroll
    for (int kb = 0; kb < 4; ++kb)
#pragma unroll
      for (int r = 0; r < 4; ++r) {
        int qrow = (lane >> 4) * 4 + r;
        int key = kb * 16 + (lane & 15);
        *(bf16_t*)(myP + ((qrow * 128 + key * 2) ^ ((qrow & 7) << 4))) = f2b(s[kb][r]);
      }
    // O += P V
#pragma unroll
    for (int ks = 0; ks < 2; ++ks) {
      int qrow = lane & 15;
      int keyp = (lane >> 4) * 8 + ks * 32;
      bf16x8 pf = *(const bf16x8*)(myP + ((qrow * 128 + keyp * 2) ^ ((qrow & 7) << 4)));
      {
        int d = (lane & 15);
        bf16x8 vf = *(const bf16x8*)(Vt + ((d * 128 + keyp * 2) ^ ((d & 7) << 4)));
        o0 = mfma16(pf, vf, o0);
      }
      {
        int d = 16 + (lane & 15);
        bf16x8 vf = *(const bf16x8*)(Vt + ((d * 128 + keyp * 2) ^ ((d & 7) << 4)));
        o1 = mfma16(pf, vf, o1);
      }
      {
        int d = 32 + (lane & 15);
        bf16x8 vf = *(const bf16x8*)(Vt + ((d * 128 + keyp * 2) ^ ((d & 7) << 4)));
        o2 = mfma16(pf, vf, o2);
      }
    }
  }
  // epilogue: normalize, gate, store y (bf16)
#pragma unroll
  for (int r = 0; r < 4; ++r) {
    float inv = 1.f / l_r[r];
    int q = qw + (lane >> 4) * 4 + r;
    float vals[3] = { o0[r], o1[r], o2[r] };
#pragma unroll
    for (int db = 0; db < 3; ++db) {
      int d = db * 16 + (lane & 15);
      int c = h * 48 + d;
      yw[((size_t)(b << 8) + q) * 384 + c] = f2b(vals[db] * inv * gate[c]);
    }
  }
}

// ---- proj GEMM: out[32768][384] = Y @ Wproj + bias, * loss_mask ----
__global__ __launch_bounds__(256) void k_gemm_proj(
    const bf16_t* __restrict__ Y, const bf16_t* __restrict__ Wt,
    const float* __restrict__ bias, const float* __restrict__ lm,
    float* __restrict__ out)
{
  __shared__ __align__(16) bf16_t As[128][32];
  __shared__ __align__(16) bf16_t Bs[128][32];
  const int tid = threadIdx.x;
  const int lane = tid & 63;
  const int wid = tid >> 6;
  const int wr = wid >> 1, wc = wid & 1;
  const int rowBase = blockIdx.x * 128;
  const int colBase = blockIdx.y * 128;
  f32x4 acc[4][4] = {};
  for (int k0 = 0; k0 < 384; k0 += 32) {
    __syncthreads();
#pragma unroll
    for (int i = 0; i < 2; ++i) {
      int c = i * 256 + tid;
      int r = c >> 2, kc = c & 3;
      *(V16*)&As[r][kc * 8] = *(const V16*)&Y[(size_t)(rowBase + r) * 384 + k0 + kc * 8];
      *(V16*)&Bs[r][kc * 8] = *(const V16*)&Wt[(size_t)(colBase + r) * 384 + k0 + kc * 8];
    }
    __syncthreads();
    bf16x8 af[4], bfr[4];
#pragma unroll
    for (int mb = 0; mb < 4; ++mb)
      af[mb] = *(const bf16x8*)&As[wr * 64 + mb * 16 + (lane & 15)][(lane >> 4) * 8];
#pragma unroll
    for (int nb = 0; nb < 4; ++nb)
      bfr[nb] = *(const bf16x8*)&Bs[wc * 64 + nb * 16 + (lane & 15)][(lane >> 4) * 8];
#pragma unroll
    for (int mb = 0; mb < 4; ++mb)
#pragma unroll
      for (int nb = 0; nb < 4; ++nb)
        acc[mb][nb] = mfma16(af[mb], bfr[nb], acc[mb][nb]);
  }
#pragma unroll
  for (int nb = 0; nb < 4; ++nb) {
    int col = colBase + wc * 64 + nb * 16 + (lane & 15);
    float bv = bias[col];
#pragma unroll
    for (int mb = 0; mb < 4; ++mb) {
#pragma unroll
      for (int r = 0; r < 4; ++r) {
        int row = rowBase + wr * 64 + mb * 16 + (lane >> 4) * 4 + r;
        out[(size_t)row * 384 + col] = (acc[mb][nb][r] + bv) * lm[row];
      }
    }
  }
}

extern "C" void kernel_launch(void* const* d_in, const int* in_sizes, int n_in,
                              void* d_out, int out_size, void* d_ws, size_t ws_size,
                              hipStream_t stream) {
  const float* x     = (const float*)d_in[0];
  const float* mem   = (const float*)d_in[1];
  const float* lm    = (const float*)d_in[2];
  const float* Wqkv  = (const float*)d_in[3];
  const float* bqkv  = (const float*)d_in[4];
  const float* Wproj = (const float*)d_in[5];
  const float* bproj = (const float*)d_in[6];
  const float* gate  = (const float*)d_in[7];
  float* out = (float*)d_out;

  char* ws = (char*)d_ws;
  bf16_t* wqkvt = (bf16_t*)ws;  ws += (size_t)1152 * 384 * 2;
  bf16_t* wprojt = (bf16_t*)ws; ws += (size_t)384 * 384 * 2;
  bf16_t* memh = (bf16_t*)ws;   ws += (size_t)8 * 512 * 64 * 2;
  bf16_t* qh = (bf16_t*)ws;     ws += (size_t)128 * 8 * 256 * 64 * 2;
  bf16_t* kh = (bf16_t*)ws;     ws += (size_t)128 * 8 * 256 * 64 * 2;
  bf16_t* vh = (bf16_t*)ws;     ws += (size_t)128 * 8 * 256 * 64 * 2;
  bf16_t* yw = (bf16_t*)ws;     ws += (size_t)32768 * 384 * 2;

  k_convT<384, 1152><<<1728, 256, 0, stream>>>(Wqkv, wqkvt);
  k_convT<384, 384><<<576, 256, 0, stream>>>(Wproj, wprojt);
  k_memh<<<1024, 256, 0, stream>>>(mem, memh);
  k_zpad<<<2048, 256, 0, stream>>>(kh);
  k_gemm_qkv<<<dim3(256, 9), 256, 0, stream>>>(x, wqkvt, bqkv, qh, kh, vh);
  k_attn<<<dim3(4, 8, 128), 256, 0, stream>>>(qh, kh, vh, memh, gate, yw);
  k_gemm_proj<<<dim3(256, 3), 256, 0, stream>>>(yw, wprojt, bproj, lm, out);
}

// Round 3
// 351.805 us; speedup vs baseline: 1.0367x; 1.0367x over previous
//
#include <hip/hip_runtime.h>
#include <hip/hip_bf16.h>

typedef __bf16 bf16_t;
typedef __bf16 bf16x4 __attribute__((ext_vector_type(4)));
typedef __bf16 bf16x8 __attribute__((ext_vector_type(8)));
typedef float f32x4 __attribute__((ext_vector_type(4)));
typedef unsigned int u32;
typedef unsigned int u32x4 __attribute__((ext_vector_type(4)));

struct alignas(16) V16 { unsigned long long x, y; };

#define SC2 0.20823437553929245f   // (1/sqrt(48)) * log2(e)
#define NEGBIG -3.0e38f

static __device__ __forceinline__ bf16_t f2b(float f) {
  union { float f; unsigned u; } v; v.f = f;
  unsigned r = v.u + 0x7fffu + ((v.u >> 16) & 1u);
  unsigned short h = (unsigned short)(r >> 16);
  return __builtin_bit_cast(bf16_t, h);
}

static __device__ __forceinline__ f32x4 mfma16(bf16x8 a, bf16x8 b, f32x4 c) {
  return __builtin_amdgcn_mfma_f32_16x16x32_bf16(a, b, c, 0, 0, 0);
}

static __device__ __forceinline__ float exp2f_(float x) {
#if __has_builtin(__builtin_amdgcn_exp2f)
  return __builtin_amdgcn_exp2f(x);
#else
  return __expf(x * 0.6931471805599453f);
#endif
}

static __device__ __forceinline__ u32 cvtpk(float lo, float hi) {
  u32 r;
  asm("v_cvt_pk_bf16_f32 %0, %1, %2" : "=v"(r) : "v"(lo), "v"(hi));
  return r;
}

// async global -> LDS, 16 bytes per lane (dest = wave-uniform base + lane*16)
static __device__ __forceinline__ void gload16(const void* g, void* l) {
  __builtin_amdgcn_global_load_lds(
      (__attribute__((address_space(1))) void*)(unsigned long long)(size_t)g,
      (__attribute__((address_space(3))) void*)(unsigned)(size_t)l,
      16, 0, 0);
}

// ---- prep: x [32768][384] f32 -> xb bf16 ----
__global__ void k_xconv(const float* __restrict__ x, bf16_t* __restrict__ xb) {
  size_t i = ((size_t)blockIdx.x * 256 + threadIdx.x) * 8;
  float4 a0 = *(const float4*)(x + i);
  float4 a1 = *(const float4*)(x + i + 4);
  bf16x8 t;
  t[0] = f2b(a0.x); t[1] = f2b(a0.y); t[2] = f2b(a0.z); t[3] = f2b(a0.w);
  t[4] = f2b(a1.x); t[5] = f2b(a1.y); t[6] = f2b(a1.z); t[7] = f2b(a1.w);
  *(bf16x8*)(xb + i) = t;
}

// ---- prep: W[k][n] (f32) -> Wt[n][k] (bf16) ----
template<int K, int N>
__global__ void k_convT(const float* __restrict__ W, bf16_t* __restrict__ Wt) {
  int idx = blockIdx.x * 256 + threadIdx.x;
  if (idx >= K * N) return;
  int n = idx / K, k = idx - n * K;
  Wt[idx] = f2b(W[k * N + n]);
}

// ---- prep: mem [512][384] f32 -> memh [8][512][64] bf16 (K side, pad zero) ----
__global__ void k_memh(const float* __restrict__ mem, bf16_t* __restrict__ memh) {
  int idx = blockIdx.x * 256 + threadIdx.x;   // 262144
  int h = idx >> 15;
  int m = (idx >> 6) & 511;
  int d = idx & 63;
  float v = (d < 48) ? mem[m * 384 + h * 48 + d] : 0.f;
  memh[idx] = f2b(v);
}

// ---- prep: mem -> memT [8][48][512] bf16 (V^T side) ----
__global__ void k_memT(const float* __restrict__ mem, bf16_t* __restrict__ memT) {
  int idx = blockIdx.x * 256 + threadIdx.x;   // 196608
  int h = idx / (48 * 512);
  int r = idx - h * 48 * 512;
  int d = r >> 9;
  int m = r & 511;
  memT[idx] = f2b(mem[m * 384 + h * 48 + d]);
}

// ---- prep: zero pad region d in [48,64) of kh [B*H*256][64] ----
__global__ void k_zpad(bf16_t* __restrict__ kh) {
  int i = blockIdx.x * 256 + threadIdx.x;     // 524288
  if (i >= 524288) return;
  int row = i >> 1, half = i & 1;
  V16 z; z.x = 0; z.y = 0;
  *(V16*)((char*)kh + (size_t)row * 128 + 96 + half * 16) = z;
}

// ---- qkv GEMM: [32768][1152] = xb @ Wt^T + bias -> scatter qh/kh (padded) + vT ----
__global__ __launch_bounds__(256) void k_gemm_qkv(
    const bf16_t* __restrict__ xb, const bf16_t* __restrict__ Wt,
    const float* __restrict__ bias,
    bf16_t* __restrict__ qh, bf16_t* __restrict__ kh, bf16_t* __restrict__ vT)
{
  __shared__ __align__(16) bf16_t As[128][32];
  __shared__ __align__(16) bf16_t Bs[128][32];
  const int tid = threadIdx.x;
  const int lane = tid & 63;
  const int wid = tid >> 6;
  const int wr = wid >> 1, wc = wid & 1;
  const int rowBase = blockIdx.x * 128;
  const int colBase = blockIdx.y * 128;
  const int srow = tid >> 2, skc = (tid & 3) * 8;
  f32x4 acc[4][4] = {};
  for (int k0 = 0; k0 < 384; k0 += 32) {
    __syncthreads();
    gload16(xb + (size_t)(rowBase + srow) * 384 + k0 + skc, (char*)As + tid * 16);
    gload16(xb + (size_t)(rowBase + 64 + srow) * 384 + k0 + skc, (char*)As + 4096 + tid * 16);
    gload16(Wt + (size_t)(colBase + srow) * 384 + k0 + skc, (char*)Bs + tid * 16);
    gload16(Wt + (size_t)(colBase + 64 + srow) * 384 + k0 + skc, (char*)Bs + 4096 + tid * 16);
    __syncthreads();
    bf16x8 af[4], bfr[4];
#pragma unroll
    for (int mb = 0; mb < 4; ++mb)
      af[mb] = *(const bf16x8*)&As[wr * 64 + mb * 16 + (lane & 15)][(lane >> 4) * 8];
#pragma unroll
    for (int nb = 0; nb < 4; ++nb)
      bfr[nb] = *(const bf16x8*)&Bs[wc * 64 + nb * 16 + (lane & 15)][(lane >> 4) * 8];
#pragma unroll
    for (int mb = 0; mb < 4; ++mb)
#pragma unroll
      for (int nb = 0; nb < 4; ++nb)
        acc[mb][nb] = mfma16(af[mb], bfr[nb], acc[mb][nb]);
  }
#pragma unroll
  for (int nb = 0; nb < 4; ++nb) {
    int col = colBase + wc * 64 + nb * 16 + (lane & 15);
    float bv = bias[col];
    int which = col / 384;
    int cc = col - which * 384;
    int h = cc / 48;
    int d = cc - h * 48;
#pragma unroll
    for (int mb = 0; mb < 4; ++mb) {
#pragma unroll
      for (int r = 0; r < 4; ++r) {
        int row = rowBase + wr * 64 + mb * 16 + (lane >> 4) * 4 + r;
        int b = row >> 8, t = row & 255;
        bf16_t val = f2b(acc[mb][nb][r] + bv);
        if (which == 0)
          qh[((size_t)(b * 8 + h) * 256 + t) * 64 + d] = val;
        else if (which == 1)
          kh[((size_t)(b * 8 + h) * 256 + t) * 64 + d] = val;
        else
          vT[((size_t)(b * 8 + h) * 48 + d) * 256 + t] = val;
      }
    }
  }
}

// ---- attention: flash-style, per (qchunk, h, b), 8 waves x 16 queries, 128-key tiles ----
__global__ __launch_bounds__(512, 4) void k_attn(
    const bf16_t* __restrict__ qh, const bf16_t* __restrict__ kh,
    const bf16_t* __restrict__ vT, const bf16_t* __restrict__ memh,
    const bf16_t* __restrict__ memT,
    const float* __restrict__ gate, bf16_t* __restrict__ yw)
{
  __shared__ __align__(16) char Ks[16384];   // K tile [key 128][d 64] bf16, xor-swizzled (^(key&7)<<4)
  __shared__ __align__(16) char Vt[12288];   // V^T tile [d 48][key 128] bf16, xor-swizzled (^(d&7)<<4)
  const int tid = threadIdx.x;
  const int lane = tid & 63;
  const int j16 = lane & 15;
  const int g = lane >> 4;
  const int w = tid >> 6;
  const int qc = blockIdx.x, h = blockIdx.y, b = blockIdx.z;
  const int bh = b * 8 + h;
  const int qw = qc * 128 + w * 16;

  // staging decode (linear LDS dest = tid*16; global src pre-swizzled)
  const int key1 = tid >> 3;                                     // rows 0..63 (then +64)
  const int doffK = (((tid & 7) << 4) ^ ((key1 & 7) << 4)) >> 1; // element offset in K row
  const int dv1 = tid >> 4;                                      // V^T rows 0..31 (then +32)
  const int kvV = (((tid & 15) << 4) ^ ((dv1 & 7) << 4)) >> 1;   // element (key) offset in V^T row

  // Q fragments (q = j16 as MFMA j-index)
  bf16x8 qf0, qf1;
  {
    const bf16_t* qp = qh + ((size_t)(bh << 8) + qw + j16) * 64 + g * 8;
    qf0 = *(const bf16x8*)qp;
    qf1 = *(const bf16x8*)(qp + 32);
  }
  float m_r = -1e30f, l_r = 0.f;
  f32x4 o0 = {}, o1 = {}, o2 = {};
  const int ntiles = (qc == 1) ? 6 : 5;

  for (int it = 0; it < ntiles; ++it) {
    const bool isMem = (it < 4);
    const int kb0 = isMem ? 0 : (it - 4) * 128;
    const bf16_t* ksrc = isMem ? memh + ((size_t)h * 512 + it * 128) * 64
                               : kh + ((size_t)(bh << 8) + kb0) * 64;
    const bf16_t* vsrc;
    int vst, vcol;
    if (isMem) { vsrc = memT + (size_t)h * 48 * 512; vst = 512; vcol = it * 128; }
    else       { vsrc = vT + (size_t)bh * 48 * 256;  vst = 256; vcol = kb0; }

    __syncthreads();  // previous tile's reads done
    gload16(ksrc + key1 * 64 + doffK,        Ks + tid * 16);
    gload16(ksrc + (key1 + 64) * 64 + doffK, Ks + 8192 + tid * 16);
    gload16(vsrc + (size_t)dv1 * vst + vcol + kvV, Vt + tid * 16);
    if (tid < 256)
      gload16(vsrc + (size_t)(dv1 + 32) * vst + vcol + kvV, Vt + 8192 + tid * 16);
    __syncthreads();  // staged data visible

    // per-wave skip: tile has no key in any of this wave's windows
    if (!isMem && (kb0 > qw + 15 || kb0 + 127 < qw - 64)) continue;

    // S^T: s[kb] holds S[q = qw+j16][key = kb0 + kb*16 + g*4 + r]
    f32x4 s[8];
#pragma unroll
    for (int kb = 0; kb < 8; ++kb) {
      const int key = kb * 16 + j16;
      const int swz = (key & 7) << 4;
      bf16x8 k0 = *(const bf16x8*)(Ks + ((key * 128 + g * 16) ^ swz));
      bf16x8 k1 = *(const bf16x8*)(Ks + ((key * 128 + 64 + g * 16) ^ swz));
      f32x4 t4 = {};
      t4 = mfma16(k0, qf0, t4);
      t4 = mfma16(k1, qf1, t4);
      s[kb] = t4;
    }

    // scale (+ causal/window mask on self tiles), row max
    float mt = NEGBIG;
    if (!isMem) {
#pragma unroll
      for (int kb = 0; kb < 8; ++kb) {
        const int dbase = kb0 + kb * 16 + g * 4 - qw - j16;  // key - q for r=0
#pragma unroll
        for (int r = 0; r < 4; ++r) {
          float sv = s[kb][r] * SC2;
          sv = ((unsigned)(dbase + r + 64) <= 64u) ? sv : NEGBIG;
          s[kb][r] = sv;
          mt = fmaxf(mt, sv);
        }
      }
    } else {
#pragma unroll
      for (int kb = 0; kb < 8; ++kb)
#pragma unroll
        for (int r = 0; r < 4; ++r) {
          float sv = s[kb][r] * SC2;
          s[kb][r] = sv;
          mt = fmaxf(mt, sv);
        }
    }
    mt = fmaxf(mt, __shfl_xor(mt, 16));
    mt = fmaxf(mt, __shfl_xor(mt, 32));

    const float mn = fmaxf(m_r, mt);
    const float alpha = exp2f_(m_r - mn);
    m_r = mn;
    o0 *= alpha; o1 *= alpha; o2 *= alpha;

    float ls = 0.f;
#pragma unroll
    for (int kb = 0; kb < 8; ++kb)
#pragma unroll
      for (int r = 0; r < 4; ++r) {
        float p = exp2f_(s[kb][r] - mn);
        s[kb][r] = p;
        ls += p;
      }
    ls += __shfl_xor(ls, 16);
    ls += __shfl_xor(ls, 32);
    l_r = l_r * alpha + ls;

    // P -> bf16 pairs, lane-local (keys kb*16 + g*4 + {r})
    u32 pku[16];
#pragma unroll
    for (int kb = 0; kb < 8; ++kb) {
      pku[kb * 2]     = cvtpk(s[kb][0], s[kb][1]);
      pku[kb * 2 + 1] = cvtpk(s[kb][2], s[kb][3]);
    }

    // O^T += V^T P : per 32-key superblock, k-dim mapping key(k)= kqq*32 + (k>>3)*4 + (k&3) + 16*((k>>2)&1)
#pragma unroll
    for (int kqq = 0; kqq < 4; ++kqq) {
      u32x4 pv = { pku[4 * kqq], pku[4 * kqq + 1], pku[4 * kqq + 2], pku[4 * kqq + 3] };
      bf16x8 pb = __builtin_bit_cast(bf16x8, pv);
#pragma unroll
      for (int db = 0; db < 3; ++db) {
        const int d = db * 16 + j16;
        const int swzd = (d & 7) << 4;
        bf16x4 lo = *(const bf16x4*)(Vt + ((d * 256 + kqq * 64 + g * 8) ^ swzd));
        bf16x4 hi = *(const bf16x4*)(Vt + ((d * 256 + kqq * 64 + 32 + g * 8) ^ swzd));
        bf16x8 av = __builtin_shufflevector(lo, hi, 0, 1, 2, 3, 4, 5, 6, 7);
        if (db == 0)      o0 = mfma16(av, pb, o0);
        else if (db == 1) o1 = mfma16(av, pb, o1);
        else              o2 = mfma16(av, pb, o2);
      }
    }
  }

  // epilogue: normalize, gate, store y^(row) (lane holds O^T[d = db*16 + g*4 + r][q = j16])
  const float inv = 1.f / l_r;
  const int q = qw + j16;
#pragma unroll
  for (int db = 0; db < 3; ++db) {
    f32x4 oo = (db == 0) ? o0 : ((db == 1) ? o1 : o2);
    const int c0 = h * 48 + db * 16 + g * 4;
    bf16x4 pack;
#pragma unroll
    for (int r = 0; r < 4; ++r)
      pack[r] = f2b(oo[r] * inv * gate[c0 + r]);
    *(bf16x4*)(yw + ((size_t)(b << 8) + q) * 384 + c0) = pack;
  }
}

// ---- proj GEMM: out[32768][384] = Y @ Wproj + bias, * loss_mask ----
__global__ __launch_bounds__(256) void k_gemm_proj(
    const bf16_t* __restrict__ Y, const bf16_t* __restrict__ Wt,
    const float* __restrict__ bias, const float* __restrict__ lm,
    float* __restrict__ out)
{
  __shared__ __align__(16) bf16_t As[128][32];
  __shared__ __align__(16) bf16_t Bs[128][32];
  const int tid = threadIdx.x;
  const int lane = tid & 63;
  const int wid = tid >> 6;
  const int wr = wid >> 1, wc = wid & 1;
  const int rowBase = blockIdx.x * 128;
  const int colBase = blockIdx.y * 128;
  const int srow = tid >> 2, skc = (tid & 3) * 8;
  f32x4 acc[4][4] = {};
  for (int k0 = 0; k0 < 384; k0 += 32) {
    __syncthreads();
    gload16(Y + (size_t)(rowBase + srow) * 384 + k0 + skc, (char*)As + tid * 16);
    gload16(Y + (size_t)(rowBase + 64 + srow) * 384 + k0 + skc, (char*)As + 4096 + tid * 16);
    gload16(Wt + (size_t)(colBase + srow) * 384 + k0 + skc, (char*)Bs + tid * 16);
    gload16(Wt + (size_t)(colBase + 64 + srow) * 384 + k0 + skc, (char*)Bs + 4096 + tid * 16);
    __syncthreads();
    bf16x8 af[4], bfr[4];
#pragma unroll
    for (int mb = 0; mb < 4; ++mb)
      af[mb] = *(const bf16x8*)&As[wr * 64 + mb * 16 + (lane & 15)][(lane >> 4) * 8];
#pragma unroll
    for (int nb = 0; nb < 4; ++nb)
      bfr[nb] = *(const bf16x8*)&Bs[wc * 64 + nb * 16 + (lane & 15)][(lane >> 4) * 8];
#pragma unroll
    for (int mb = 0; mb < 4; ++mb)
#pragma unroll
      for (int nb = 0; nb < 4; ++nb)
        acc[mb][nb] = mfma16(af[mb], bfr[nb], acc[mb][nb]);
  }
#pragma unroll
  for (int nb = 0; nb < 4; ++nb) {
    int col = colBase + wc * 64 + nb * 16 + (lane & 15);
    float bv = bias[col];
#pragma unroll
    for (int mb = 0; mb < 4; ++mb) {
#pragma unroll
      for (int r = 0; r < 4; ++r) {
        int row = rowBase + wr * 64 + mb * 16 + (lane >> 4) * 4 + r;
        out[(size_t)row * 384 + col] = (acc[mb][nb][r] + bv) * lm[row];
      }
    }
  }
}

extern "C" void kernel_launch(void* const* d_in, const int* in_sizes, int n_in,
                              void* d_out, int out_size, void* d_ws, size_t ws_size,
                              hipStream_t stream) {
  const float* x     = (const float*)d_in[0];
  const float* mem   = (const float*)d_in[1];
  const float* lm    = (const float*)d_in[2];
  const float* Wqkv  = (const float*)d_in[3];
  const float* bqkv  = (const float*)d_in[4];
  const float* Wproj = (const float*)d_in[5];
  const float* bproj = (const float*)d_in[6];
  const float* gate  = (const float*)d_in[7];
  float* out = (float*)d_out;

  char* ws = (char*)d_ws;
  bf16_t* wqkvt = (bf16_t*)ws;  ws += (size_t)1152 * 384 * 2;
  bf16_t* wprojt = (bf16_t*)ws; ws += (size_t)384 * 384 * 2;
  bf16_t* memh = (bf16_t*)ws;   ws += (size_t)8 * 512 * 64 * 2;
  bf16_t* memT = (bf16_t*)ws;   ws += (size_t)8 * 48 * 512 * 2;
  bf16_t* qh = (bf16_t*)ws;     ws += (size_t)128 * 8 * 256 * 64 * 2;
  bf16_t* kh = (bf16_t*)ws;     ws += (size_t)128 * 8 * 256 * 64 * 2;
  bf16_t* vT = (bf16_t*)ws;     ws += (size_t)128 * 8 * 48 * 256 * 2;
  bf16_t* xb = (bf16_t*)ws;     // aliased: xb (pre-GEMM) and yw (post-attn)
  bf16_t* yw = xb;

  k_xconv<<<6144, 256, 0, stream>>>(x, xb);
  k_convT<384, 1152><<<1728, 256, 0, stream>>>(Wqkv, wqkvt);
  k_convT<384, 384><<<576, 256, 0, stream>>>(Wproj, wprojt);
  k_memh<<<1024, 256, 0, stream>>>(mem, memh);
  k_memT<<<768, 256, 0, stream>>>(mem, memT);
  k_zpad<<<2048, 256, 0, stream>>>(kh);
  k_gemm_qkv<<<dim3(256, 9), 256, 0, stream>>>(xb, wqkvt, bqkv, qh, kh, vT);
  k_attn<<<dim3(2, 8, 128), 512, 0, stream>>>(qh, kh, vT, memh, memT, gate, yw);
  k_gemm_proj<<<dim3(256, 3), 256, 0, stream>>>(yw, wprojt, bproj, lm, out);
}

// Round 5
// 309.269 us; speedup vs baseline: 1.1793x; 1.1375x over previous
//
#include <hip/hip_runtime.h>
#include <hip/hip_bf16.h>

typedef __bf16 bf16_t;
typedef __bf16 bf16x4 __attribute__((ext_vector_type(4)));
typedef __bf16 bf16x8 __attribute__((ext_vector_type(8)));
typedef float f32x4 __attribute__((ext_vector_type(4)));
typedef unsigned int u32;
typedef unsigned int u32x4 __attribute__((ext_vector_type(4)));

struct alignas(16) V16 { unsigned long long x, y; };

#define SC2 0.20823437553929245f   // (1/sqrt(48)) * log2(e)
#define NEGBIG -3.0e38f

static __device__ __forceinline__ bf16_t f2b(float f) {
  union { float f; unsigned u; } v; v.f = f;
  unsigned r = v.u + 0x7fffu + ((v.u >> 16) & 1u);
  unsigned short h = (unsigned short)(r >> 16);
  return __builtin_bit_cast(bf16_t, h);
}

static __device__ __forceinline__ f32x4 mfma16(bf16x8 a, bf16x8 b, f32x4 c) {
  return __builtin_amdgcn_mfma_f32_16x16x32_bf16(a, b, c, 0, 0, 0);
}

static __device__ __forceinline__ float exp2f_(float x) {
#if __has_builtin(__builtin_amdgcn_exp2f)
  return __builtin_amdgcn_exp2f(x);
#else
  return __expf(x * 0.6931471805599453f);
#endif
}

static __device__ __forceinline__ u32 cvtpk(float lo, float hi) {
  u32 r;
  asm("v_cvt_pk_bf16_f32 %0, %1, %2" : "=v"(r) : "v"(lo), "v"(hi));
  return r;
}

// async global -> LDS, 16 bytes per lane (dest = wave-uniform base + lane*16)
static __device__ __forceinline__ void gload16(const void* g, void* l) {
  __builtin_amdgcn_global_load_lds(
      (__attribute__((address_space(1))) void*)(unsigned long long)(size_t)g,
      (__attribute__((address_space(3))) void*)(unsigned)(size_t)l,
      16, 0, 0);
}

// ---- prep: x [32768][384] f32 -> xb bf16 ----
__global__ void k_xconv(const float* __restrict__ x, bf16_t* __restrict__ xb) {
  size_t i = ((size_t)blockIdx.x * 256 + threadIdx.x) * 8;
  float4 a0 = *(const float4*)(x + i);
  float4 a1 = *(const float4*)(x + i + 4);
  bf16x8 t;
  t[0] = f2b(a0.x); t[1] = f2b(a0.y); t[2] = f2b(a0.z); t[3] = f2b(a0.w);
  t[4] = f2b(a1.x); t[5] = f2b(a1.y); t[6] = f2b(a1.z); t[7] = f2b(a1.w);
  *(bf16x8*)(xb + i) = t;
}

// ---- prep: Wqkv [384][1152] f32 -> Wp [1536][384] bf16, padded col space ----
// c2 = sec*512 + h*64 + d ; d>=48 rows are zero (=> q/k/v pads compute to exact 0)
__global__ void k_wprep(const float* __restrict__ W, bf16_t* __restrict__ Wp) {
  int idx = blockIdx.x * 256 + threadIdx.x;   // 1536*384
  if (idx >= 1536 * 384) return;
  int c2 = idx / 384, k = idx - c2 * 384;
  int sec = c2 >> 9, within = c2 & 511, hh = within >> 6, d = within & 63;
  float v = (d < 48) ? W[k * 1152 + sec * 384 + hh * 48 + d] : 0.f;
  Wp[idx] = f2b(v);
}

__global__ void k_bprep(const float* __restrict__ bq, float* __restrict__ bp) {
  int c2 = blockIdx.x * 256 + threadIdx.x;    // 1536
  if (c2 >= 1536) return;
  int sec = c2 >> 9, within = c2 & 511, hh = within >> 6, d = within & 63;
  bp[c2] = (d < 48) ? bq[sec * 384 + hh * 48 + d] : 0.f;
}

// ---- prep: W[k][n] (f32) -> Wt[n][k] (bf16) ----
template<int K, int N>
__global__ void k_convT(const float* __restrict__ W, bf16_t* __restrict__ Wt) {
  int idx = blockIdx.x * 256 + threadIdx.x;
  if (idx >= K * N) return;
  int n = idx / K, k = idx - n * K;
  Wt[idx] = f2b(W[k * N + n]);
}

// ---- prep: mem [512][384] f32 -> memh [8][512][64] bf16 (K side, pad zero) ----
__global__ void k_memh(const float* __restrict__ mem, bf16_t* __restrict__ memh) {
  int idx = blockIdx.x * 256 + threadIdx.x;   // 262144
  int h = idx >> 15;
  int m = (idx >> 6) & 511;
  int d = idx & 63;
  float v = (d < 48) ? mem[m * 384 + h * 48 + d] : 0.f;
  memh[idx] = f2b(v);
}

// ---- prep: mem -> memT [8][48][512] bf16 (V^T side) ----
__global__ void k_memT(const float* __restrict__ mem, bf16_t* __restrict__ memT) {
  int idx = blockIdx.x * 256 + threadIdx.x;   // 196608
  int h = idx / (48 * 512);
  int r = idx - h * 48 * 512;
  int d = r >> 9;
  int m = r & 511;
  memT[idx] = f2b(mem[m * 384 + h * 48 + d]);
}

// ---- qkv GEMM: [32768][1536p] = xb @ Wp^T + biasp -> qh/kh ([bh][t][64]) + vT ([bh][48][256]) ----
__global__ __launch_bounds__(256) void k_gemm_qkv(
    const bf16_t* __restrict__ xb, const bf16_t* __restrict__ Wt,
    const float* __restrict__ biasp,
    bf16_t* __restrict__ qh, bf16_t* __restrict__ kh, bf16_t* __restrict__ vT)
{
  __shared__ __align__(16) char smem[32768];  // [2][A 8KB | B 8KB]; epilogue reuses as C[128][128]
  const int tid = threadIdx.x;
  const int lane = tid & 63;
  const int j16 = lane & 15;
  const int g = lane >> 4;
  const int wid = tid >> 6;
  const int wr = wid >> 1, wc = wid & 1;
  const int rowBase = blockIdx.x * 128;
  const int colBase = blockIdx.y * 128;
  const int srow = tid >> 2, skc = (tid & 3) * 8;

  f32x4 acc[4][4] = {};

#define STAGE_G(k0, bufidx) do { \
    char* A_ = smem + (bufidx) * 16384; \
    char* B_ = A_ + 8192; \
    gload16(xb + (size_t)(rowBase + srow) * 384 + (k0) + skc, A_ + tid * 16); \
    gload16(xb + (size_t)(rowBase + 64 + srow) * 384 + (k0) + skc, A_ + 4096 + tid * 16); \
    gload16(Wt + (size_t)(colBase + srow) * 384 + (k0) + skc, B_ + tid * 16); \
    gload16(Wt + (size_t)(colBase + 64 + srow) * 384 + (k0) + skc, B_ + 4096 + tid * 16); \
  } while (0)

  STAGE_G(0, 0);
  __syncthreads();
  for (int i = 0; i < 12; ++i) {
    const int cur = i & 1;
    if (i < 11) STAGE_G((i + 1) * 32, cur ^ 1);
    const bf16_t* As = (const bf16_t*)(smem + cur * 16384);
    const bf16_t* Bs = As + 4096;
    bf16x8 af[4], bfr[4];
#pragma unroll
    for (int mb = 0; mb < 4; ++mb)
      af[mb] = *(const bf16x8*)&As[(wr * 64 + mb * 16 + j16) * 32 + g * 8];
#pragma unroll
    for (int nb = 0; nb < 4; ++nb)
      bfr[nb] = *(const bf16x8*)&Bs[(wc * 64 + nb * 16 + j16) * 32 + g * 8];
#pragma unroll
    for (int mb = 0; mb < 4; ++mb)
#pragma unroll
      for (int nb = 0; nb < 4; ++nb)
        acc[mb][nb] = mfma16(af[mb], bfr[nb], acc[mb][nb]);
    __syncthreads();
  }
#undef STAGE_G

  const int sec = colBase >> 9;            // 0=q, 1=k, 2=v
  const int b = rowBase >> 8;
  const int tBase = rowBase & 255;
  if (sec < 2) {
    // retile through LDS -> contiguous 16KB per head, coalesced 16B stores
    bf16_t* dst0 = (sec == 0) ? qh : kh;
    const int hBase = (colBase - sec * 512) >> 6;
    bf16_t* C = (bf16_t*)smem;             // [128][128]
#pragma unroll
    for (int nb = 0; nb < 4; ++nb) {
      const int c_loc = wc * 64 + nb * 16 + j16;
      const float bv = biasp[colBase + c_loc];
#pragma unroll
      for (int mb = 0; mb < 4; ++mb)
#pragma unroll
        for (int r = 0; r < 4; ++r) {
          const int t_loc = wr * 64 + mb * 16 + g * 4 + r;
          C[t_loc * 128 + c_loc] = f2b(acc[mb][nb][r] + bv);
        }
    }
    __syncthreads();
#pragma unroll
    for (int ch = 0; ch < 2; ++ch) {
      const int h = hBase + ch;
      bf16_t* dst = dst0 + (((size_t)(b * 8 + h) * 256 + tBase) << 6);
#pragma unroll
      for (int p = 0; p < 4; ++p) {
        const int k = tid + p * 256;       // 0..1023 16B chunks
        const int t_loc = k >> 3;
        V16 v = *(const V16*)&C[t_loc * 128 + ch * 64 + (k & 7) * 8];
        *(V16*)&dst[(size_t)k * 8] = v;
      }
    }
  } else {
    // v sector: pack 4 consecutive t per lane -> 8B stores into vT [bh][48][256]
#pragma unroll
    for (int nb = 0; nb < 4; ++nb) {
      const int cl = wc * 64 + nb * 16 + j16;
      const int vcol = (colBase - 1024) + cl;
      const int hh = vcol >> 6, d = vcol & 63;
      const float bv = biasp[colBase + cl];
      if (d < 48) {
#pragma unroll
        for (int mb = 0; mb < 4; ++mb) {
          bf16x4 pk;
#pragma unroll
          for (int r = 0; r < 4; ++r) pk[r] = f2b(acc[mb][nb][r] + bv);
          const int t0 = tBase + wr * 64 + mb * 16 + g * 4;
          *(bf16x4*)&vT[((size_t)(b * 8 + hh) * 48 + d) * 256 + t0] = pk;
        }
      }
    }
  }
}

// ---- attention: flash-style, double-buffered, 8 waves x 16 q, 128-key tiles ----
__global__ __launch_bounds__(512, 2) void k_attn(
    const bf16_t* __restrict__ qh, const bf16_t* __restrict__ kh,
    const bf16_t* __restrict__ vT, const bf16_t* __restrict__ memh,
    const bf16_t* __restrict__ memT,
    const float* __restrict__ gate, bf16_t* __restrict__ yp)
{
  __shared__ __align__(16) char smem[57344];  // [2][ K 16KB | V 12KB ]
  const int tid = threadIdx.x;
  const int lane = tid & 63;
  const int j16 = lane & 15;
  const int g = lane >> 4;
  const int w = tid >> 6;
  const int qc = blockIdx.x, h = blockIdx.y, b = blockIdx.z;
  const int bh = b * 8 + h;
  const int qw = qc * 128 + w * 16;

  // staging decode (linear LDS dest = tid*16; global src pre-swizzled)
  const int key1 = tid >> 3;
  const int doffK = (((tid & 7) << 4) ^ ((key1 & 7) << 4)) >> 1;
  const int dv1 = tid >> 4;
  const int kvV = (((tid & 15) << 4) ^ ((dv1 & 7) << 4)) >> 1;

  bf16x8 qf0, qf1;
  {
    const bf16_t* qp = qh + ((size_t)(bh << 8) + qw + j16) * 64 + g * 8;
    qf0 = *(const bf16x8*)qp;
    qf1 = *(const bf16x8*)(qp + 32);
  }
  float m_r = -1e30f, l_r = 0.f;
  f32x4 o0 = {}, o1 = {}, o2 = {};
  const int nt = (qc == 1) ? 6 : 5;

#define STAGE_A(it_, buf_) do { \
    const bool im_ = (it_) < 4; \
    const int kb_ = im_ ? 0 : ((it_) - 4) * 128; \
    const bf16_t* ks_ = im_ ? memh + ((size_t)h * 512 + (it_) * 128) * 64 \
                            : kh + ((size_t)(bh << 8) + kb_) * 64; \
    const bf16_t* vs_; int vst_, vc_; \
    if (im_) { vs_ = memT + (size_t)h * 48 * 512; vst_ = 512; vc_ = (it_) * 128; } \
    else     { vs_ = vT + (size_t)bh * 48 * 256;  vst_ = 256; vc_ = kb_; } \
    char* K_ = smem + (buf_) * 28672; \
    char* V_ = K_ + 16384; \
    gload16(ks_ + key1 * 64 + doffK,        K_ + tid * 16); \
    gload16(ks_ + (key1 + 64) * 64 + doffK, K_ + 8192 + tid * 16); \
    gload16(vs_ + (size_t)dv1 * vst_ + vc_ + kvV, V_ + tid * 16); \
    if (tid < 256) \
      gload16(vs_ + (size_t)(dv1 + 32) * vst_ + vc_ + kvV, V_ + 8192 + tid * 16); \
  } while (0)

  STAGE_A(0, 0);
  __syncthreads();

  for (int it = 0; it < nt; ++it) {
    const int cur = it & 1;
    if (it + 1 < nt) STAGE_A(it + 1, cur ^ 1);

    const bool isMem = (it < 4);
    const int kb0 = (it - 4) * 128;
    if (isMem || !(kb0 > qw + 15 || kb0 + 127 < qw - 64)) {
      const char* K = smem + cur * 28672;
      const char* V = K + 16384;

      // S^T: s[kb][r] = S[q=qw+j16][key = kb0 + kb*16 + g*4 + r]
      f32x4 s[8];
#pragma unroll
      for (int kb = 0; kb < 8; ++kb) {
        const int key = kb * 16 + j16;
        const int swz = (key & 7) << 4;
        bf16x8 k0v = *(const bf16x8*)(K + ((key * 128 + g * 16) ^ swz));
        bf16x8 k1v = *(const bf16x8*)(K + ((key * 128 + 64 + g * 16) ^ swz));
        f32x4 t4 = {};
        t4 = mfma16(k0v, qf0, t4);
        t4 = mfma16(k1v, qf1, t4);
        s[kb] = t4;
      }

      // scale (+ causal/window mask on self tiles), row max  [round-3 math]
      float mt = NEGBIG;
      if (!isMem) {
#pragma unroll
        for (int kb = 0; kb < 8; ++kb) {
          const int dbase = kb0 + kb * 16 + g * 4 - qw - j16;
#pragma unroll
          for (int r = 0; r < 4; ++r) {
            float sv = s[kb][r] * SC2;
            sv = ((unsigned)(dbase + r + 64) <= 64u) ? sv : NEGBIG;
            s[kb][r] = sv;
            mt = fmaxf(mt, sv);
          }
        }
      } else {
#pragma unroll
        for (int kb = 0; kb < 8; ++kb)
#pragma unroll
          for (int r = 0; r < 4; ++r) {
            float sv = s[kb][r] * SC2;
            s[kb][r] = sv;
            mt = fmaxf(mt, sv);
          }
      }
      mt = fmaxf(mt, __shfl_xor(mt, 16));
      mt = fmaxf(mt, __shfl_xor(mt, 32));

      const float mn = fmaxf(m_r, mt);
      const float alpha = exp2f_(m_r - mn);
      m_r = mn;
      o0 *= alpha; o1 *= alpha; o2 *= alpha;

      float ls = 0.f;
#pragma unroll
      for (int kb = 0; kb < 8; ++kb)
#pragma unroll
        for (int r = 0; r < 4; ++r) {
          float p = exp2f_(s[kb][r] - mn);
          s[kb][r] = p;
          ls += p;
        }
      ls += __shfl_xor(ls, 16);
      ls += __shfl_xor(ls, 32);
      l_r = l_r * alpha + ls;

      // P -> bf16 pairs, lane-local (keys kb*16 + g*4 + {r})
      u32 pku[16];
#pragma unroll
      for (int kb = 0; kb < 8; ++kb) {
        pku[kb * 2]     = cvtpk(s[kb][0], s[kb][1]);
        pku[kb * 2 + 1] = cvtpk(s[kb][2], s[kb][3]);
      }

      // O^T += V^T P
#pragma unroll
      for (int kqq = 0; kqq < 4; ++kqq) {
        u32x4 pv = { pku[4 * kqq], pku[4 * kqq + 1], pku[4 * kqq + 2], pku[4 * kqq + 3] };
        bf16x8 pb = __builtin_bit_cast(bf16x8, pv);
#pragma unroll
        for (int db = 0; db < 3; ++db) {
          const int d = db * 16 + j16;
          const int swzd = (d & 7) << 4;
          bf16x4 lo = *(const bf16x4*)(V + ((d * 256 + kqq * 64 + g * 8) ^ swzd));
          bf16x4 hi = *(const bf16x4*)(V + ((d * 256 + kqq * 64 + 32 + g * 8) ^ swzd));
          bf16x8 av = __builtin_shufflevector(lo, hi, 0, 1, 2, 3, 4, 5, 6, 7);
          if (db == 0)      o0 = mfma16(av, pb, o0);
          else if (db == 1) o1 = mfma16(av, pb, o1);
          else              o2 = mfma16(av, pb, o2);
        }
      }
    }
    __syncthreads();
  }
#undef STAGE_A

  // epilogue: normalize, gate, write yp [bh][256][48] (lane holds O^T[d=db*16+g*4+r][q=j16])
  const float inv = 1.0f / l_r;
  const int q = qw + j16;
#pragma unroll
  for (int db = 0; db < 3; ++db) {
    f32x4 oo = (db == 0) ? o0 : ((db == 1) ? o1 : o2);
    const int c0 = db * 16 + g * 4;
    bf16x4 pack;
#pragma unroll
    for (int r = 0; r < 4; ++r)
      pack[r] = f2b(oo[r] * inv * gate[h * 48 + c0 + r]);
    *(bf16x4*)(yp + ((size_t)(bh << 8) + q) * 48 + c0) = pack;
  }
}

// ---- proj GEMM: out[32768][384] = Yp @ Wproj + bias, * loss_mask ----
__global__ __launch_bounds__(256) void k_gemm_proj(
    const bf16_t* __restrict__ yp, const bf16_t* __restrict__ Wt,
    const float* __restrict__ bias, const float* __restrict__ lm,
    float* __restrict__ out)
{
  __shared__ __align__(16) char smem[32768];
  const int tid = threadIdx.x;
  const int lane = tid & 63;
  const int j16 = lane & 15;
  const int g = lane >> 4;
  const int wid = tid >> 6;
  const int wr = wid >> 1, wc = wid & 1;
  const int rowBase = blockIdx.x * 128;
  const int colBase = blockIdx.y * 128;
  const int srow = tid >> 2, skc = (tid & 3) * 8;
  const int bb = rowBase >> 8, tb = rowBase & 255;

  f32x4 acc[4][4] = {};

#define STAGE_P(k0, bufidx) do { \
    char* A_ = smem + (bufidx) * 16384; \
    char* B_ = A_ + 8192; \
    const int c_ = (k0) + skc; \
    const int hh_ = (int)(((unsigned)c_ * 1366u) >> 16); \
    const int d_ = c_ - hh_ * 48; \
    gload16(yp + ((size_t)(bb * 8 + hh_) * 256 + tb + srow) * 48 + d_, A_ + tid * 16); \
    gload16(yp + ((size_t)(bb * 8 + hh_) * 256 + tb + 64 + srow) * 48 + d_, A_ + 4096 + tid * 16); \
    gload16(Wt + (size_t)(colBase + srow) * 384 + (k0) + skc, B_ + tid * 16); \
    gload16(Wt + (size_t)(colBase + 64 + srow) * 384 + (k0) + skc, B_ + 4096 + tid * 16); \
  } while (0)

  STAGE_P(0, 0);
  __syncthreads();
  for (int i = 0; i < 12; ++i) {
    const int cur = i & 1;
    if (i < 11) STAGE_P((i + 1) * 32, cur ^ 1);
    const bf16_t* As = (const bf16_t*)(smem + cur * 16384);
    const bf16_t* Bs = As + 4096;
    bf16x8 af[4], bfr[4];
#pragma unroll
    for (int mb = 0; mb < 4; ++mb)
      af[mb] = *(const bf16x8*)&As[(wr * 64 + mb * 16 + j16) * 32 + g * 8];
#pragma unroll
    for (int nb = 0; nb < 4; ++nb)
      bfr[nb] = *(const bf16x8*)&Bs[(wc * 64 + nb * 16 + j16) * 32 + g * 8];
#pragma unroll
    for (int mb = 0; mb < 4; ++mb)
#pragma unroll
      for (int nb = 0; nb < 4; ++nb)
        acc[mb][nb] = mfma16(af[mb], bfr[nb], acc[mb][nb]);
    __syncthreads();
  }
#undef STAGE_P

#pragma unroll
  for (int nb = 0; nb < 4; ++nb) {
    int col = colBase + wc * 64 + nb * 16 + j16;
    float bv = bias[col];
#pragma unroll
    for (int mb = 0; mb < 4; ++mb) {
#pragma unroll
      for (int r = 0; r < 4; ++r) {
        int row = rowBase + wr * 64 + mb * 16 + g * 4 + r;
        out[(size_t)row * 384 + col] = (acc[mb][nb][r] + bv) * lm[row];
      }
    }
  }
}

extern "C" void kernel_launch(void* const* d_in, const int* in_sizes, int n_in,
                              void* d_out, int out_size, void* d_ws, size_t ws_size,
                              hipStream_t stream) {
  const float* x     = (const float*)d_in[0];
  const float* mem   = (const float*)d_in[1];
  const float* lm    = (const float*)d_in[2];
  const float* Wqkv  = (const float*)d_in[3];
  const float* bqkv  = (const float*)d_in[4];
  const float* Wproj = (const float*)d_in[5];
  const float* bproj = (const float*)d_in[6];
  const float* gate  = (const float*)d_in[7];
  float* out = (float*)d_out;

  char* ws = (char*)d_ws;
  bf16_t* wqkvt = (bf16_t*)ws;  ws += (size_t)1536 * 384 * 2;
  float*  biasp = (float*)ws;   ws += (size_t)1536 * 4;
  bf16_t* wprojt = (bf16_t*)ws; ws += (size_t)384 * 384 * 2;
  bf16_t* memh = (bf16_t*)ws;   ws += (size_t)8 * 512 * 64 * 2;
  bf16_t* memT = (bf16_t*)ws;   ws += (size_t)8 * 48 * 512 * 2;
  bf16_t* qh = (bf16_t*)ws;     ws += (size_t)128 * 8 * 256 * 64 * 2;
  bf16_t* kh = (bf16_t*)ws;     ws += (size_t)128 * 8 * 256 * 64 * 2;
  bf16_t* vT = (bf16_t*)ws;     ws += (size_t)128 * 8 * 48 * 256 * 2;
  bf16_t* xb = (bf16_t*)ws;     // aliased: xb (pre-GEMM) and yp (post-attn)
  bf16_t* yp = xb;

  k_xconv<<<6144, 256, 0, stream>>>(x, xb);
  k_wprep<<<2304, 256, 0, stream>>>(Wqkv, wqkvt);
  k_bprep<<<6, 256, 0, stream>>>(bqkv, biasp);
  k_convT<384, 384><<<576, 256, 0, stream>>>(Wproj, wprojt);
  k_memh<<<1024, 256, 0, stream>>>(mem, memh);
  k_memT<<<768, 256, 0, stream>>>(mem, memT);
  k_gemm_qkv<<<dim3(256, 12), 256, 0, stream>>>(xb, wqkvt, biasp, qh, kh, vT);
  k_attn<<<dim3(2, 8, 128), 512, 0, stream>>>(qh, kh, vT, memh, memT, gate, yp);
  k_gemm_proj<<<dim3(256, 3), 256, 0, stream>>>(yp, wprojt, bproj, lm, out);
}

// Round 7
// 276.571 us; speedup vs baseline: 1.3187x; 1.1182x over previous
//
#include <hip/hip_runtime.h>
#include <hip/hip_bf16.h>

typedef __bf16 bf16_t;
typedef __bf16 bf16x4 __attribute__((ext_vector_type(4)));
typedef __bf16 bf16x8 __attribute__((ext_vector_type(8)));
typedef float f32x4 __attribute__((ext_vector_type(4)));
typedef unsigned int u32;
typedef unsigned int u32x4 __attribute__((ext_vector_type(4)));

struct alignas(16) V16 { unsigned long long x, y; };

#define SC2 0.20823437553929245f   // (1/sqrt(48)) * log2(e)  -- folded into q at qkv epilogue
#define NEGBIG -3.0e38f

static __device__ __forceinline__ bf16_t f2b(float f) {
  union { float f; unsigned u; } v; v.f = f;
  unsigned r = v.u + 0x7fffu + ((v.u >> 16) & 1u);
  unsigned short h = (unsigned short)(r >> 16);
  return __builtin_bit_cast(bf16_t, h);
}

static __device__ __forceinline__ f32x4 mfma16(bf16x8 a, bf16x8 b, f32x4 c) {
  return __builtin_amdgcn_mfma_f32_16x16x32_bf16(a, b, c, 0, 0, 0);
}

static __device__ __forceinline__ float exp2f_(float x) {
#if __has_builtin(__builtin_amdgcn_exp2f)
  return __builtin_amdgcn_exp2f(x);
#else
  return __expf(x * 0.6931471805599453f);
#endif
}

static __device__ __forceinline__ u32 cvtpk(float lo, float hi) {
  u32 r;
  asm("v_cvt_pk_bf16_f32 %0, %1, %2" : "=v"(r) : "v"(lo), "v"(hi));
  return r;
}

// async global -> LDS, 16 bytes per lane (dest = wave-uniform base + lane*16)
static __device__ __forceinline__ void gload16(const void* g, void* l) {
  __builtin_amdgcn_global_load_lds(
      (__attribute__((address_space(1))) void*)(unsigned long long)(size_t)g,
      (__attribute__((address_space(3))) void*)(unsigned)(size_t)l,
      16, 0, 0);
}

// ---- prep: x [32768][384] f32 -> xb bf16 ----
__global__ void k_xconv(const float* __restrict__ x, bf16_t* __restrict__ xb) {
  size_t i = ((size_t)blockIdx.x * 256 + threadIdx.x) * 8;
  float4 a0 = *(const float4*)(x + i);
  float4 a1 = *(const float4*)(x + i + 4);
  bf16x8 t;
  t[0] = f2b(a0.x); t[1] = f2b(a0.y); t[2] = f2b(a0.z); t[3] = f2b(a0.w);
  t[4] = f2b(a1.x); t[5] = f2b(a1.y); t[6] = f2b(a1.z); t[7] = f2b(a1.w);
  *(bf16x8*)(xb + i) = t;
}

// ---- fused prep: weight transposes + mem layouts + q/k pad zeroing ----
// sections (exact total 2097152 = 8192*256):
//  [0,442368)        convT Wqkv -> wqkvt [1152][384]
//  [.,+147456)       convT Wproj -> wprojt [384][384]
//  [.,+262144)       memh [8][512][64] (pad zero)
//  [.,+196608)       memT [8][48][512]
//  [.,+524288)       zero qh pads d in [48,64)
//  [.,+524288)       zero kh pads d in [48,64)
__global__ void k_prep(const float* __restrict__ Wqkv, const float* __restrict__ Wproj,
                       const float* __restrict__ mem,
                       bf16_t* __restrict__ wqkvt, bf16_t* __restrict__ wprojt,
                       bf16_t* __restrict__ memh, bf16_t* __restrict__ memT,
                       bf16_t* __restrict__ qh, bf16_t* __restrict__ kh) {
  int idx = blockIdx.x * 256 + threadIdx.x;
  if (idx < 442368) {
    int n = idx / 384, k = idx - n * 384;
    wqkvt[idx] = f2b(Wqkv[k * 1152 + n]);
  } else if ((idx -= 442368) < 147456) {
    int n = idx / 384, k = idx - n * 384;
    wprojt[idx] = f2b(Wproj[k * 384 + n]);
  } else if ((idx -= 147456) < 262144) {
    int h = idx >> 15, m = (idx >> 6) & 511, d = idx & 63;
    memh[idx] = f2b(d < 48 ? mem[m * 384 + h * 48 + d] : 0.f);
  } else if ((idx -= 262144) < 196608) {
    int h = idx / 24576;
    int r = idx - h * 24576;
    int d = r >> 9, m = r & 511;
    memT[idx] = f2b(mem[m * 384 + h * 48 + d]);
  } else if ((idx -= 196608) < 524288) {
    int row = idx >> 1, half = idx & 1;
    V16 z; z.x = 0; z.y = 0;
    *(V16*)((char*)qh + (size_t)row * 128 + 96 + half * 16) = z;
  } else {
    idx -= 524288;
    int row = idx >> 1, half = idx & 1;
    V16 z; z.x = 0; z.y = 0;
    *(V16*)((char*)kh + (size_t)row * 128 + 96 + half * 16) = z;
  }
}

// ---- qkv GEMM (unpadded N=1152): each 128-col tile lies wholly in one section (384=3*128) ----
// q section pre-scaled by SC2; q/k retiled via LDS to [bh][t][64p]; v stored direct to vT [bh][48][256]
__global__ __launch_bounds__(256) void k_gemm_qkv(
    const bf16_t* __restrict__ xb, const bf16_t* __restrict__ Wt,
    const float* __restrict__ bias,
    bf16_t* __restrict__ qh, bf16_t* __restrict__ kh, bf16_t* __restrict__ vT)
{
  __shared__ __align__(16) char smem[32768];  // [2][A 8KB | B 8KB]; epilogue reuses as C[128][128]
  const int tid = threadIdx.x;
  const int lane = tid & 63;
  const int j16 = lane & 15;
  const int g = lane >> 4;
  const int wid = tid >> 6;
  const int wr = wid >> 1, wc = wid & 1;
  const int rowBase = blockIdx.x * 128;
  const int by = blockIdx.y;               // 0..8
  const int colBase = by * 128;
  const int sec = by / 3;                  // 0=q,1=k,2=v (tiles never straddle sections)
  const int srow = tid >> 2, skc = (tid & 3) * 8;

  f32x4 acc[4][4] = {};

#define STAGE_G(k0, bufidx) do { \
    char* A_ = smem + (bufidx) * 16384; \
    char* B_ = A_ + 8192; \
    gload16(xb + (size_t)(rowBase + srow) * 384 + (k0) + skc, A_ + tid * 16); \
    gload16(xb + (size_t)(rowBase + 64 + srow) * 384 + (k0) + skc, A_ + 4096 + tid * 16); \
    gload16(Wt + (size_t)(colBase + srow) * 384 + (k0) + skc, B_ + tid * 16); \
    gload16(Wt + (size_t)(colBase + 64 + srow) * 384 + (k0) + skc, B_ + 4096 + tid * 16); \
  } while (0)

  STAGE_G(0, 0);
  __syncthreads();
  for (int i = 0; i < 12; ++i) {
    const int cur = i & 1;
    if (i < 11) STAGE_G((i + 1) * 32, cur ^ 1);
    const bf16_t* As = (const bf16_t*)(smem + cur * 16384);
    const bf16_t* Bs = As + 4096;
    bf16x8 af[4], bfr[4];
#pragma unroll
    for (int mb = 0; mb < 4; ++mb)
      af[mb] = *(const bf16x8*)&As[(wr * 64 + mb * 16 + j16) * 32 + g * 8];
#pragma unroll
    for (int nb = 0; nb < 4; ++nb)
      bfr[nb] = *(const bf16x8*)&Bs[(wc * 64 + nb * 16 + j16) * 32 + g * 8];
#pragma unroll
    for (int mb = 0; mb < 4; ++mb)
#pragma unroll
      for (int nb = 0; nb < 4; ++nb)
        acc[mb][nb] = mfma16(af[mb], bfr[nb], acc[mb][nb]);
    __syncthreads();
  }
#undef STAGE_G

  const int b = rowBase >> 8;
  const int tBase = rowBase & 255;
  if (sec < 2) {
    bf16_t* dst0 = (sec == 0) ? qh : kh;
    const float scl = (sec == 0) ? SC2 : 1.0f;
    const int colSec = colBase - sec * 384;   // 0,128,256 within section
    bf16_t* C = (bf16_t*)smem;                // [128][128]
#pragma unroll
    for (int nb = 0; nb < 4; ++nb) {
      const int c_loc = wc * 64 + nb * 16 + j16;
      const float bv = bias[colBase + c_loc];
#pragma unroll
      for (int mb = 0; mb < 4; ++mb)
#pragma unroll
        for (int r = 0; r < 4; ++r) {
          const int t_loc = wr * 64 + mb * 16 + g * 4 + r;
          C[t_loc * 128 + c_loc] = f2b((acc[mb][nb][r] + bv) * scl);
        }
    }
    __syncthreads();
    // 2048 16B chunks: chunk k -> (t_loc = k>>4, col = colSec + (k&15)*8); 8-col chunk stays in one head
#pragma unroll
    for (int p = 0; p < 8; ++p) {
      const int k = tid + p * 256;
      const int t_loc = k >> 4;
      const int col = colSec + (k & 15) * 8;
      const int h = (int)(((unsigned)col * 1366u) >> 16);
      const int d0 = col - h * 48;
      V16 v = *(const V16*)&C[t_loc * 128 + (k & 15) * 8];
      *(V16*)&dst0[(((size_t)(b * 8 + h) * 256 + tBase + t_loc) << 6) + d0] = v;
    }
  } else {
    // v: direct 8B stores into vT [bh][48][256]; every col valid
#pragma unroll
    for (int nb = 0; nb < 4; ++nb) {
      const int cl = wc * 64 + nb * 16 + j16;
      const int vcol = (colBase - 768) + cl;
      const int hh = (int)(((unsigned)vcol * 1366u) >> 16);
      const int d = vcol - hh * 48;
      const float bv = bias[colBase + cl];
#pragma unroll
      for (int mb = 0; mb < 4; ++mb) {
        bf16x4 pk;
#pragma unroll
        for (int r = 0; r < 4; ++r) pk[r] = f2b(acc[mb][nb][r] + bv);
        const int t0 = tBase + wr * 64 + mb * 16 + g * 4;
        *(bf16x4*)&vT[((size_t)(b * 8 + hh) * 48 + d) * 256 + t0] = pk;
      }
    }
  }
}

// ---- attention: 256 q per block (8 waves x 2 qgroups x 16 q), double-buffered 128-key tiles ----
__global__ __launch_bounds__(512, 2) void k_attn(
    const bf16_t* __restrict__ qh, const bf16_t* __restrict__ kh,
    const bf16_t* __restrict__ vT, const bf16_t* __restrict__ memh,
    const bf16_t* __restrict__ memT,
    const float* __restrict__ gate, bf16_t* __restrict__ yp)
{
  __shared__ __align__(16) char smem[57344];  // [2][ K 16KB | V 12KB ]
  const int tid = threadIdx.x;
  const int lane = tid & 63;
  const int j16 = lane & 15;
  const int g = lane >> 4;
  const int w = tid >> 6;
  const int h = blockIdx.x, b = blockIdx.y;
  const int bh = b * 8 + h;

  // staging decode (linear LDS dest = tid*16; global src pre-swizzled)
  const int key1 = tid >> 3;
  const int doffK = (((tid & 7) << 4) ^ ((key1 & 7) << 4)) >> 1;
  const int dv1 = tid >> 4;
  const int kvV = (((tid & 15) << 4) ^ ((dv1 & 7) << 4)) >> 1;

  bf16x8 qfa[2], qfb[2];
#pragma unroll
  for (int qg = 0; qg < 2; ++qg) {
    const bf16_t* qp = qh + ((size_t)(bh << 8) + qg * 128 + w * 16 + j16) * 64 + g * 8;
    qfa[qg] = *(const bf16x8*)qp;
    qfb[qg] = *(const bf16x8*)(qp + 32);
  }
  float m_r[2] = {-1e30f, -1e30f}, l_r[2] = {0.f, 0.f};
  f32x4 o[2][3] = {};

#define STAGE_A(it_, buf_) do { \
    const bool im_ = (it_) < 4; \
    const int kb_ = im_ ? 0 : ((it_) - 4) * 128; \
    const bf16_t* ks_ = im_ ? memh + ((size_t)h * 512 + (it_) * 128) * 64 \
                            : kh + ((size_t)(bh << 8) + kb_) * 64; \
    const bf16_t* vs_; int vst_, vc_; \
    if (im_) { vs_ = memT + (size_t)h * 48 * 512; vst_ = 512; vc_ = (it_) * 128; } \
    else     { vs_ = vT + (size_t)bh * 48 * 256;  vst_ = 256; vc_ = kb_; } \
    char* K_ = smem + (buf_) * 28672; \
    char* V_ = K_ + 16384; \
    gload16(ks_ + key1 * 64 + doffK,        K_ + tid * 16); \
    gload16(ks_ + (key1 + 64) * 64 + doffK, K_ + 8192 + tid * 16); \
    gload16(vs_ + (size_t)dv1 * vst_ + vc_ + kvV, V_ + tid * 16); \
    if (tid < 256) \
      gload16(vs_ + (size_t)(dv1 + 32) * vst_ + vc_ + kvV, V_ + 8192 + tid * 16); \
  } while (0)

  STAGE_A(0, 0);
  __syncthreads();

  for (int it = 0; it < 6; ++it) {
    const int cur = it & 1;
    if (it < 5) STAGE_A(it + 1, cur ^ 1);

    const bool isMem = (it < 4);
    const int kb0 = (it - 4) * 128;
    const char* K = smem + cur * 28672;
    const char* V = K + 16384;

#pragma unroll
    for (int qg = 0; qg < 2; ++qg) {
      const int qw = qg * 128 + w * 16;
      if (!isMem && (kb0 > qw + 15 || kb0 + 127 < qw - 64)) continue;

      // S^T (already log2e*scale domain via pre-scaled q)
      f32x4 s[8];
#pragma unroll
      for (int kb = 0; kb < 8; ++kb) {
        const int key = kb * 16 + j16;
        const int swz = (key & 7) << 4;
        bf16x8 k0v = *(const bf16x8*)(K + ((key * 128 + g * 16) ^ swz));
        bf16x8 k1v = *(const bf16x8*)(K + ((key * 128 + 64 + g * 16) ^ swz));
        f32x4 t4 = {};
        t4 = mfma16(k0v, qfa[qg], t4);
        t4 = mfma16(k1v, qfb[qg], t4);
        s[kb] = t4;
      }

      if (!isMem) {
#pragma unroll
        for (int kb = 0; kb < 8; ++kb) {
          const int dbase = kb0 + kb * 16 + g * 4 - qw - j16;
#pragma unroll
          for (int r = 0; r < 4; ++r)
            s[kb][r] = ((unsigned)(dbase + r + 64) <= 64u) ? s[kb][r] : NEGBIG;
        }
      }
      f32x4 mv = s[0];
#pragma unroll
      for (int kb = 1; kb < 8; ++kb) {
        mv[0] = fmaxf(mv[0], s[kb][0]);
        mv[1] = fmaxf(mv[1], s[kb][1]);
        mv[2] = fmaxf(mv[2], s[kb][2]);
        mv[3] = fmaxf(mv[3], s[kb][3]);
      }
      float mt = fmaxf(fmaxf(mv[0], mv[1]), fmaxf(mv[2], mv[3]));
      mt = fmaxf(mt, __shfl_xor(mt, 16));
      mt = fmaxf(mt, __shfl_xor(mt, 32));

      const float mn = fmaxf(m_r[qg], mt);
      const float alpha = exp2f_(m_r[qg] - mn);
      m_r[qg] = mn;
#pragma unroll
      for (int db = 0; db < 3; ++db) o[qg][db] *= alpha;

      float ls = 0.f;
#pragma unroll
      for (int kb = 0; kb < 8; ++kb)
#pragma unroll
        for (int r = 0; r < 4; ++r) {
          float p = exp2f_(s[kb][r] - mn);
          s[kb][r] = p;
          ls += p;
        }
      ls += __shfl_xor(ls, 16);
      ls += __shfl_xor(ls, 32);
      l_r[qg] = l_r[qg] * alpha + ls;

      u32 pku[16];
#pragma unroll
      for (int kb = 0; kb < 8; ++kb) {
        pku[kb * 2]     = cvtpk(s[kb][0], s[kb][1]);
        pku[kb * 2 + 1] = cvtpk(s[kb][2], s[kb][3]);
      }

#pragma unroll
      for (int kqq = 0; kqq < 4; ++kqq) {
        u32x4 pv = { pku[4 * kqq], pku[4 * kqq + 1], pku[4 * kqq + 2], pku[4 * kqq + 3] };
        bf16x8 pb = __builtin_bit_cast(bf16x8, pv);
#pragma unroll
        for (int db = 0; db < 3; ++db) {
          const int d = db * 16 + j16;
          const int swzd = (d & 7) << 4;
          bf16x4 lo = *(const bf16x4*)(V + ((d * 256 + kqq * 64 + g * 8) ^ swzd));
          bf16x4 hi = *(const bf16x4*)(V + ((d * 256 + kqq * 64 + 32 + g * 8) ^ swzd));
          bf16x8 av = __builtin_shufflevector(lo, hi, 0, 1, 2, 3, 4, 5, 6, 7);
          o[qg][db] = mfma16(av, pb, o[qg][db]);
        }
      }
    }
    __syncthreads();
  }
#undef STAGE_A

  // epilogue: normalize, gate, write yp [bh][256][48]
#pragma unroll
  for (int qg = 0; qg < 2; ++qg) {
    const float inv = 1.0f / l_r[qg];
    const int q = qg * 128 + w * 16 + j16;
#pragma unroll
    for (int db = 0; db < 3; ++db) {
      const int c0 = db * 16 + g * 4;
      bf16x4 pack;
#pragma unroll
      for (int r = 0; r < 4; ++r)
        pack[r] = f2b(o[qg][db][r] * inv * gate[h * 48 + c0 + r]);
      *(bf16x4*)(yp + ((size_t)(bh << 8) + q) * 48 + c0) = pack;
    }
  }
}

// ---- proj GEMM: out[32768][384] = Yp @ Wproj + bias, * loss_mask ----
__global__ __launch_bounds__(256) void k_gemm_proj(
    const bf16_t* __restrict__ yp, const bf16_t* __restrict__ Wt,
    const float* __restrict__ bias, const float* __restrict__ lm,
    float* __restrict__ out)
{
  __shared__ __align__(16) char smem[32768];
  const int tid = threadIdx.x;
  const int lane = tid & 63;
  const int j16 = lane & 15;
  const int g = lane >> 4;
  const int wid = tid >> 6;
  const int wr = wid >> 1, wc = wid & 1;
  const int rowBase = blockIdx.x * 128;
  const int colBase = blockIdx.y * 128;
  const int srow = tid >> 2, skc = (tid & 3) * 8;
  const int bb = rowBase >> 8, tb = rowBase & 255;

  f32x4 acc[4][4] = {};

#define STAGE_P(k0, bufidx) do { \
    char* A_ = smem + (bufidx) * 16384; \
    char* B_ = A_ + 8192; \
    const int c_ = (k0) + skc; \
    const int hh_ = (int)(((unsigned)c_ * 1366u) >> 16); \
    const int d_ = c_ - hh_ * 48; \
    gload16(yp + ((size_t)(bb * 8 + hh_) * 256 + tb + srow) * 48 + d_, A_ + tid * 16); \
    gload16(yp + ((size_t)(bb * 8 + hh_) * 256 + tb + 64 + srow) * 48 + d_, A_ + 4096 + tid * 16); \
    gload16(Wt + (size_t)(colBase + srow) * 384 + (k0) + skc, B_ + tid * 16); \
    gload16(Wt + (size_t)(colBase + 64 + srow) * 384 + (k0) + skc, B_ + 4096 + tid * 16); \
  } while (0)

  STAGE_P(0, 0);
  __syncthreads();
  for (int i = 0; i < 12; ++i) {
    const int cur = i & 1;
    if (i < 11) STAGE_P((i + 1) * 32, cur ^ 1);
    const bf16_t* As = (const bf16_t*)(smem + cur * 16384);
    const bf16_t* Bs = As + 4096;
    bf16x8 af[4], bfr[4];
#pragma unroll
    for (int mb = 0; mb < 4; ++mb)
      af[mb] = *(const bf16x8*)&As[(wr * 64 + mb * 16 + j16) * 32 + g * 8];
#pragma unroll
    for (int nb = 0; nb < 4; ++nb)
      bfr[nb] = *(const bf16x8*)&Bs[(wc * 64 + nb * 16 + j16) * 32 + g * 8];
#pragma unroll
    for (int mb = 0; mb < 4; ++mb)
#pragma unroll
      for (int nb = 0; nb < 4; ++nb)
        acc[mb][nb] = mfma16(af[mb], bfr[nb], acc[mb][nb]);
    __syncthreads();
  }
#undef STAGE_P

#pragma unroll
  for (int nb = 0; nb < 4; ++nb) {
    int col = colBase + wc * 64 + nb * 16 + j16;
    float bv = bias[col];
#pragma unroll
    for (int mb = 0; mb < 4; ++mb) {
#pragma unroll
      for (int r = 0; r < 4; ++r) {
        int row = rowBase + wr * 64 + mb * 16 + g * 4 + r;
        out[(size_t)row * 384 + col] = (acc[mb][nb][r] + bv) * lm[row];
      }
    }
  }
}

extern "C" void kernel_launch(void* const* d_in, const int* in_sizes, int n_in,
                              void* d_out, int out_size, void* d_ws, size_t ws_size,
                              hipStream_t stream) {
  const float* x     = (const float*)d_in[0];
  const float* mem   = (const float*)d_in[1];
  const float* lm    = (const float*)d_in[2];
  const float* Wqkv  = (const float*)d_in[3];
  const float* bqkv  = (const float*)d_in[4];
  const float* Wproj = (const float*)d_in[5];
  const float* bproj = (const float*)d_in[6];
  const float* gate  = (const float*)d_in[7];
  float* out = (float*)d_out;

  char* ws = (char*)d_ws;
  bf16_t* wqkvt = (bf16_t*)ws;  ws += (size_t)1152 * 384 * 2;
  bf16_t* wprojt = (bf16_t*)ws; ws += (size_t)384 * 384 * 2;
  bf16_t* memh = (bf16_t*)ws;   ws += (size_t)8 * 512 * 64 * 2;
  bf16_t* memT = (bf16_t*)ws;   ws += (size_t)8 * 48 * 512 * 2;
  bf16_t* qh = (bf16_t*)ws;     ws += (size_t)128 * 8 * 256 * 64 * 2;
  bf16_t* kh = (bf16_t*)ws;     ws += (size_t)128 * 8 * 256 * 64 * 2;
  bf16_t* vT = (bf16_t*)ws;     ws += (size_t)128 * 8 * 48 * 256 * 2;
  bf16_t* xb = (bf16_t*)ws;     // aliased: xb (pre-GEMM) and yp (post-attn)
  bf16_t* yp = xb;

  k_xconv<<<6144, 256, 0, stream>>>(x, xb);
  k_prep<<<8192, 256, 0, stream>>>(Wqkv, Wproj, mem, wqkvt, wprojt, memh, memT, qh, kh);
  k_gemm_qkv<<<dim3(256, 9), 256, 0, stream>>>(xb, wqkvt, bqkv, qh, kh, vT);
  k_attn<<<dim3(8, 128), 512, 0, stream>>>(qh, kh, vT, memh, memT, gate, yp);
  k_gemm_proj<<<dim3(256, 3), 256, 0, stream>>>(yp, wprojt, bproj, lm, out);
}